// Round 1
// baseline (1218.544 us; speedup 1.0000x reference)
//
#include <hip/hip_runtime.h>
#include <cfloat>
#include <cstdint>

// ---------------- problem constants ----------------
#define NC 1536   // 3*H concatenated projection width

// d_out float offsets: emb[16,1024] | out[16] | smiles_attn_pool[16,2048] | seqs_attn_pool[16,128]
#define OUT_EMB 0
#define OUT_OUT 16384
#define OUT_A1  16400
#define OUT_A2  49168

// ws byte offsets
#define WS_NRM_S   0u
#define WS_NRM_M   32768u
#define WS_PART    65536u
#define WS_PARTM   327680u
#define WS_BCAT    360448u
#define WS_LOG1    366592u
#define WS_PP1     505856u
#define WS_POOL2   768000u
#define WS_EMB     800768u
#define WS_H1      866304u
#define WS_H2      931840u
#define WS_WCT     1048576u
#define WS_SMISNB  2621440u
#define WS_PSMIS   4718592u
#define WS_SEQSOUT 11010048u
#define WS_SEQSNB  15204352u
#define WS_PSEQS   48758784u
#define WS_SMILOUT WS_SEQSNB          // seqs_nb dead after GEMM1; reuse for smiles_out
#define WS_S2      149422080u          // ws total need ~216.5 MB

typedef float f32x4 __attribute__((ext_vector_type(4)));
typedef __bf16 bf16x8 __attribute__((ext_vector_type(8)));

__device__ __forceinline__ float bf2f(unsigned short h) {
  return __uint_as_float(((unsigned int)h) << 16);
}
__device__ __forceinline__ unsigned short f2bf(float f) {
  unsigned int u = __float_as_uint(f);
  return (unsigned short)((u + 0x7FFFu + ((u >> 16) & 1u)) >> 16);
}
__device__ __forceinline__ void gld16(const unsigned short* g, unsigned short* l) {
  __builtin_amdgcn_global_load_lds(
      (__attribute__((address_space(1))) unsigned int*)(uintptr_t)g,
      (__attribute__((address_space(3))) unsigned int*)l, 16, 0, 0);
}

// ---------------- column-wise l2 norms (axis=1) ----------------
__global__ __launch_bounds__(256) void knorm_part(const float* __restrict__ x, float* __restrict__ part,
                                                  int L, int SL, int NS) {
  int ls = blockIdx.x, hc = blockIdx.y, b = blockIdx.z, t = threadIdx.x;
  int h = hc * 256 + t;
  const float* xp = x + (size_t)b * L * 512 + h;
  float acc = 0.f;
  int l0 = ls * SL;
  for (int l = 0; l < SL; ++l) {
    float v = xp[(size_t)(l0 + l) * 512];
    acc += v * v;
  }
  part[(((size_t)b * 2 + hc) * NS + ls) * 256 + t] = acc;
}

__global__ __launch_bounds__(256) void knorm_fin(const float* __restrict__ part, float* __restrict__ inv, int NS) {
  int bh = blockIdx.x, t = threadIdx.x;
  float s = 0.f;
  for (int j = 0; j < NS; ++j) s += part[((size_t)bh * NS + j) * 256 + t];
  inv[(size_t)bh * 256 + t] = 1.f / fmaxf(sqrtf(s), 1e-12f);
}

__global__ __launch_bounds__(256) void kcast(const float* __restrict__ x, const float* __restrict__ inv,
                                             unsigned short* __restrict__ o, int shiftB, int total) {
  int i4 = (blockIdx.x * 256 + threadIdx.x) * 4;
  if (i4 >= total) return;
  int b = i4 >> shiftB;
  float4 v = *(const float4*)(x + i4);
  float4 nv = *(const float4*)(inv + (b << 9) + (i4 & 511));
  ushort4 r;
  r.x = f2bf(v.x * nv.x); r.y = f2bf(v.y * nv.y);
  r.z = f2bf(v.z * nv.z); r.w = f2bf(v.w * nv.w);
  *(ushort4*)(o + i4) = r;
}

// ---------------- weight prep: WcatT[1536][512] bf16 (B^T layout), bcat ----------------
__global__ __launch_bounds__(256) void kprepw(const float* __restrict__ Wq, const float* __restrict__ Wk,
                                              const float* __restrict__ Wv, unsigned short* __restrict__ WT) {
  __shared__ float T[32][33];
  int ti = blockIdx.x, tj = blockIdx.y, m = blockIdx.z;
  const float* W = m == 0 ? Wq : (m == 1 ? Wk : Wv);
  int c = threadIdx.x & 31, r0 = threadIdx.x >> 5;
#pragma unroll
  for (int j = 0; j < 4; ++j) {
    int r = r0 + j * 8;
    T[r][c] = W[(size_t)(ti * 32 + r) * 512 + tj * 32 + c];
  }
  __syncthreads();
#pragma unroll
  for (int j = 0; j < 4; ++j) {
    int r = r0 + j * 8;
    WT[(size_t)(m * 512 + tj * 32 + r) * 512 + ti * 32 + c] = f2bf(T[c][r]);
  }
}

__global__ void kprepb(const float* bq, const float* bk, const float* bv, float* bcat) {
  int i = blockIdx.x * 256 + threadIdx.x;
  if (i >= 1536) return;
  bcat[i] = i < 512 ? bq[i] : (i < 1024 ? bk[i - 512] : bv[i - 1024]);
}

// ---------------- bf16 MFMA GEMM: C[M,N] = A[M,K] @ Bt[N,K]^T + bias ----------------
__global__ __launch_bounds__(256) void kgemm(const unsigned short* __restrict__ A,
                                             const unsigned short* __restrict__ Bt,
                                             const float* __restrict__ bias,
                                             unsigned short* __restrict__ C,
                                             int K, int N) {
  __shared__ unsigned short As[128 * 32], Bs[128 * 32];
  int tid = threadIdx.x, lane = tid & 63, wave = tid >> 6;
  int m0 = blockIdx.y * 128, n0 = blockIdx.x * 128;
  f32x4 acc[4][4] = {};
  int wm = (wave >> 1) * 64, wn = (wave & 1) * 64;
  int frow = lane & 15, fk = (lane >> 4) * 8;
  for (int k0 = 0; k0 < K; k0 += 32) {
    if (k0) __syncthreads();
#pragma unroll
    for (int j = 0; j < 2; ++j) {
      int ch = j * 256 + tid;
      int row = ch >> 2, kc = (ch & 3) * 8;
      gld16(A + (size_t)(m0 + row) * K + k0 + kc, As + ch * 8);
      gld16(Bt + (size_t)(n0 + row) * K + k0 + kc, Bs + ch * 8);
    }
    __syncthreads();
    bf16x8 af[4], bfv[4];
#pragma unroll
    for (int mt = 0; mt < 4; ++mt) af[mt] = *(const bf16x8*)&As[(wm + mt * 16 + frow) * 32 + fk];
#pragma unroll
    for (int nt = 0; nt < 4; ++nt) bfv[nt] = *(const bf16x8*)&Bs[(wn + nt * 16 + frow) * 32 + fk];
#pragma unroll
    for (int mt = 0; mt < 4; ++mt)
#pragma unroll
      for (int nt = 0; nt < 4; ++nt)
        acc[mt][nt] = __builtin_amdgcn_mfma_f32_16x16x32_bf16(af[mt], bfv[nt], acc[mt][nt], 0, 0, 0);
  }
  int q = lane >> 4, c15 = lane & 15;
#pragma unroll
  for (int mt = 0; mt < 4; ++mt)
#pragma unroll
    for (int nt = 0; nt < 4; ++nt) {
      int col = n0 + wn + nt * 16 + c15;
      float bv = bias ? bias[col] : 0.f;
#pragma unroll
      for (int r = 0; r < 4; ++r) {
        int row = m0 + wm + mt * 16 + q * 4 + r;
        C[(size_t)row * N + col] = f2bf(acc[mt][nt][r] + bv);
      }
    }
}

// ---------------- fusion 1: Q=seqs(2048) K,V=smis(128); top-32 of 128 ----------------
__global__ __launch_bounds__(256) void kfusion1(const unsigned short* __restrict__ Pseqs,
                                                const unsigned short* __restrict__ Psmis,
                                                unsigned short* __restrict__ smil) {
  __shared__ unsigned short Qs[64 * 72];
  __shared__ unsigned short Ks[128 * 72];
  __shared__ unsigned short Vs[128 * 72];
  __shared__ unsigned short Sc[64 * 132];   // bf16 scores
  int tid = threadIdx.x, lane = tid & 63, wave = tid >> 6;
  int lt = blockIdx.x, h = blockIdx.y, b = blockIdx.z;
  int l0 = lt * 64;
  for (int ch = tid; ch < 512; ch += 256) {
    int r = ch >> 3, e8 = (ch & 7) * 8;
    *(uint4*)&Qs[r * 72 + e8] = *(const uint4*)&Pseqs[(size_t)(b * 2048 + l0 + r) * NC + h * 64 + e8];
  }
  for (int ch = tid; ch < 1024; ch += 256) {
    int r = ch >> 3, e8 = (ch & 7) * 8;
    size_t base = (size_t)(b * 128 + r) * NC + h * 64 + e8;
    *(uint4*)&Ks[r * 72 + e8] = *(const uint4*)&Psmis[base + 512];
    *(uint4*)&Vs[r * 72 + e8] = *(const uint4*)&Psmis[base + 1024];
  }
  __syncthreads();
  {
    int frow = lane & 15, fk8 = (lane >> 4) * 8, q = lane >> 4;
    f32x4 acc[8] = {};
#pragma unroll
    for (int ks = 0; ks < 2; ++ks) {
      bf16x8 a = *(const bf16x8*)&Qs[(wave * 16 + frow) * 72 + ks * 32 + fk8];
#pragma unroll
      for (int nt = 0; nt < 8; ++nt) {
        bf16x8 bb = *(const bf16x8*)&Ks[(nt * 16 + frow) * 72 + ks * 32 + fk8];
        acc[nt] = __builtin_amdgcn_mfma_f32_16x16x32_bf16(a, bb, acc[nt], 0, 0, 0);
      }
    }
#pragma unroll
    for (int nt = 0; nt < 8; ++nt)
#pragma unroll
      for (int r = 0; r < 4; ++r)
        Sc[(wave * 16 + q * 4 + r) * 132 + nt * 16 + frow] = f2bf(acc[nt][r]);
  }
  __syncthreads();
  for (int i = 0; i < 16; ++i) {
    int row = wave * 16 + i;
    unsigned int u0 = ((unsigned int)Sc[row * 132 + lane]) << 16;
    unsigned int u1 = ((unsigned int)Sc[row * 132 + 64 + lane]) << 16;
    u0 = (u0 & 0x80000000u) ? ~u0 : (u0 | 0x80000000u);
    u1 = (u1 & 0x80000000u) ? ~u1 : (u1 | 0x80000000u);
    unsigned int key0 = (u0 & 0xFFFFFF80u) | (127u - lane);
    unsigned int key1 = (u1 & 0xFFFFFF80u) | (127u - (lane + 64));
    // bitonic sort descending over 128 elems: e0 = lane, e1 = lane|64
#pragma unroll
    for (unsigned int k = 2; k <= 128; k <<= 1) {
#pragma unroll
      for (unsigned int j = k >> 1; j > 0; j >>= 1) {
        if (j == 64) {
          unsigned int mx = key0 > key1 ? key0 : key1;
          unsigned int mn = key0 > key1 ? key1 : key0;
          key0 = mx; key1 = mn;
        } else {
          unsigned int p0 = (unsigned int)__shfl_xor((int)key0, (int)j);
          unsigned int p1 = (unsigned int)__shfl_xor((int)key1, (int)j);
          bool low = (lane & j) == 0u;
          bool d0 = (((unsigned int)lane & k) == 0u) == low;
          bool d1 = ((((unsigned int)lane + 64u) & k) == 0u) == low;
          key0 = d0 ? (key0 > p0 ? key0 : p0) : (key0 > p0 ? p0 : key0);
          key1 = d1 ? (key1 > p1 ? key1 : p1) : (key1 > p1 ? p1 : key1);
        }
      }
    }
    int sidx = 127 - (int)(key0 & 127u);
    float sv = bf2f(Sc[row * 132 + sidx]);
    float mx = __shfl(sv, 0);
    float p = (lane < 32) ? __expf((sv - mx) * 0.125f) : 0.f;
    float den = p;
#pragma unroll
    for (int d = 1; d < 64; d <<= 1) den += __shfl_xor(den, d);
    p /= den;
    float outv = 0.f;
#pragma unroll
    for (int t = 0; t < 32; ++t) {
      float pt = __shfl(p, t);
      int st = __shfl(sidx, t);
      outv += pt * bf2f(Vs[st * 72 + lane]);
    }
    smil[(size_t)(b * 2048 + l0 + row) * 512 + h * 64 + lane] = f2bf(outv);
  }
}

// ---------------- fusion 2 scores: S2[bh][l 128][s 2048] bf16 ----------------
__global__ __launch_bounds__(256) void kf2scores(const unsigned short* __restrict__ Psmis,
                                                 const unsigned short* __restrict__ Pseqs,
                                                 unsigned short* __restrict__ S2) {
  __shared__ unsigned short As[128 * 32], Bs[128 * 32];
  int tid = threadIdx.x, lane = tid & 63, wave = tid >> 6;
  int st = blockIdx.x, bh = blockIdx.y;
  int b = bh >> 3, h = bh & 7;
  int s0 = st * 128;
  const unsigned short* Abase = Psmis + (size_t)b * 128 * NC + h * 64;
  const unsigned short* Bbase = Pseqs + (size_t)b * 2048 * NC + 512 + h * 64;
  f32x4 acc[4][4] = {};
  int wm = (wave >> 1) * 64, wn = (wave & 1) * 64;
  int frow = lane & 15, fk = (lane >> 4) * 8;
  for (int k0 = 0; k0 < 64; k0 += 32) {
    if (k0) __syncthreads();
#pragma unroll
    for (int j = 0; j < 2; ++j) {
      int ch = j * 256 + tid;
      int row = ch >> 2, kc = (ch & 3) * 8;
      gld16(Abase + (size_t)row * NC + k0 + kc, As + ch * 8);
      gld16(Bbase + (size_t)(s0 + row) * NC + k0 + kc, Bs + ch * 8);
    }
    __syncthreads();
    bf16x8 af[4], bfv[4];
#pragma unroll
    for (int mt = 0; mt < 4; ++mt) af[mt] = *(const bf16x8*)&As[(wm + mt * 16 + frow) * 32 + fk];
#pragma unroll
    for (int nt = 0; nt < 4; ++nt) bfv[nt] = *(const bf16x8*)&Bs[(wn + nt * 16 + frow) * 32 + fk];
#pragma unroll
    for (int mt = 0; mt < 4; ++mt)
#pragma unroll
      for (int nt = 0; nt < 4; ++nt)
        acc[mt][nt] = __builtin_amdgcn_mfma_f32_16x16x32_bf16(af[mt], bfv[nt], acc[mt][nt], 0, 0, 0);
  }
  int q = lane >> 4, c15 = lane & 15;
  unsigned short* outp = S2 + (size_t)bh * 128 * 2048;
#pragma unroll
  for (int mt = 0; mt < 4; ++mt)
#pragma unroll
    for (int nt = 0; nt < 4; ++nt)
#pragma unroll
      for (int r = 0; r < 4; ++r)
        outp[(size_t)(wm + mt * 16 + q * 4 + r) * 2048 + s0 + wn + nt * 16 + c15] = f2bf(acc[mt][nt][r]);
}

// ---------------- fusion 2 select: top-32 of 2048 per row + softmax + AV ----------------
__global__ __launch_bounds__(256) void kf2select(const unsigned short* __restrict__ S2,
                                                 const unsigned short* __restrict__ Pseqs,
                                                 float* __restrict__ seqs_out) {
  int tid = threadIdx.x, lane = tid & 63, wave = tid >> 6;
  for (int i = 0; i < 4; ++i) {
    int rid = blockIdx.x * 16 + wave * 4 + i;
    int l = rid & 127, bh = rid >> 7;
    int h = bh & 7, b = bh >> 3;
    const unsigned short* rowp = S2 + (size_t)rid * 2048;
    float v[32];
#pragma unroll
    for (int j = 0; j < 32; j += 8) {
      uint4 pk = *(const uint4*)&rowp[lane * 32 + j];
      v[j + 0] = bf2f((unsigned short)(pk.x & 0xFFFFu)); v[j + 1] = bf2f((unsigned short)(pk.x >> 16));
      v[j + 2] = bf2f((unsigned short)(pk.y & 0xFFFFu)); v[j + 3] = bf2f((unsigned short)(pk.y >> 16));
      v[j + 4] = bf2f((unsigned short)(pk.z & 0xFFFFu)); v[j + 5] = bf2f((unsigned short)(pk.z >> 16));
      v[j + 6] = bf2f((unsigned short)(pk.w & 0xFFFFu)); v[j + 7] = bf2f((unsigned short)(pk.w >> 16));
    }
    float lm = -FLT_MAX; int li = 0;
#pragma unroll
    for (int j = 0; j < 32; ++j) if (v[j] > lm) { lm = v[j]; li = j; }
    float pv = 0.f; int ps = 0;
    for (int t = 0; t < 32; ++t) {
      float bvv = lm; unsigned int bs = (unsigned int)(lane * 32 + li);
#pragma unroll
      for (int d = 32; d; d >>= 1) {
        float ov = __shfl_xor(bvv, d);
        unsigned int os = (unsigned int)__shfl_xor((int)bs, d);
        if (ov > bvv || (ov == bvv && os < bs)) { bvv = ov; bs = os; }
      }
      if (lane == t) { pv = bvv; ps = (int)bs; }
      if ((int)(bs >> 5) == lane) {
        int rj = (int)(bs & 31u);
        lm = -FLT_MAX; li = 0;
#pragma unroll
        for (int j = 0; j < 32; ++j) {
          if (j == rj) v[j] = -FLT_MAX;
          if (v[j] > lm) { lm = v[j]; li = j; }
        }
      }
    }
    float mxv = __shfl(pv, 0);
    float p = (lane < 32) ? __expf((pv - mxv) * 0.125f) : 0.f;
    float den = p;
#pragma unroll
    for (int d = 1; d < 64; d <<= 1) den += __shfl_xor(den, d);
    p /= den;
    float outv = 0.f;
#pragma unroll
    for (int t = 0; t < 32; ++t) {
      float pt = __shfl(p, t);
      int stt = __shfl(ps, t);
      outv += pt * bf2f(Pseqs[(size_t)(b * 2048 + stt) * NC + 1024 + h * 64 + lane]);
    }
    seqs_out[(size_t)(b * 128 + l) * 512 + h * 64 + lane] = outv;
  }
}

// ---------------- pooling ----------------
__device__ __forceinline__ float dot8(uint4 pk, const float* w) {
  float s = bf2f((unsigned short)(pk.x & 0xFFFFu)) * w[0] + bf2f((unsigned short)(pk.x >> 16)) * w[1];
  s += bf2f((unsigned short)(pk.y & 0xFFFFu)) * w[2] + bf2f((unsigned short)(pk.y >> 16)) * w[3];
  s += bf2f((unsigned short)(pk.z & 0xFFFFu)) * w[4] + bf2f((unsigned short)(pk.z >> 16)) * w[5];
  s += bf2f((unsigned short)(pk.w & 0xFFFFu)) * w[6] + bf2f((unsigned short)(pk.w >> 16)) * w[7];
  return s;
}

__global__ __launch_bounds__(256) void kpool1a(const unsigned short* __restrict__ x,
                                               const float* __restrict__ wp, const float* __restrict__ bp,
                                               float* __restrict__ logits) {
  int tid = threadIdx.x, lane = tid & 63, wave = tid >> 6;
  int r = blockIdx.x * 4 + wave;
  uint4 pk = *(const uint4*)(x + (size_t)r * 512 + lane * 8);
  float acc = dot8(pk, wp + lane * 8);
#pragma unroll
  for (int d = 1; d < 64; d <<= 1) acc += __shfl_xor(acc, d);
  if (lane == 0) logits[r] = acc + bp[0];
}

__global__ __launch_bounds__(256) void kpool1b(const unsigned short* __restrict__ x,
                                               const float* __restrict__ logits,
                                               float* __restrict__ aout, float* __restrict__ pp) {
  __shared__ float red[256];
  __shared__ float aS[256];
  int t = threadIdx.x;
  int b = blockIdx.x >> 3, ls = blockIdx.x & 7;
  const float* lg = logits + b * 2048;
  float lm = -FLT_MAX;
  for (int j = t; j < 2048; j += 256) lm = fmaxf(lm, lg[j]);
  red[t] = lm; __syncthreads();
  for (int s = 128; s > 0; s >>= 1) { if (t < s) red[t] = fmaxf(red[t], red[t + s]); __syncthreads(); }
  float M = red[0]; __syncthreads();
  float sm = 0.f;
  for (int j = t; j < 2048; j += 256) sm += __expf(lg[j] - M);
  red[t] = sm; __syncthreads();
  for (int s = 128; s > 0; s >>= 1) { if (t < s) red[t] += red[t + s]; __syncthreads(); }
  float D = red[0];
  int l0 = ls * 256;
  float a = __expf(lg[l0 + t] - M) / D;
  aS[t] = a;
  aout[b * 2048 + l0 + t] = a;
  __syncthreads();
  float acc0 = 0.f, acc1 = 0.f;
  const unsigned short* xb = x + ((size_t)b * 2048 + l0) * 512;
#pragma unroll 4
  for (int ll = 0; ll < 256; ++ll) {
    float av = aS[ll];
    acc0 += av * bf2f(xb[(size_t)ll * 512 + t]);
    acc1 += av * bf2f(xb[(size_t)ll * 512 + t + 256]);
  }
  pp[(size_t)(b * 8 + ls) * 512 + t] = acc0;
  pp[(size_t)(b * 8 + ls) * 512 + t + 256] = acc1;
}

__global__ __launch_bounds__(256) void kpool2(const float* __restrict__ x,
                                              const float* __restrict__ wp, const float* __restrict__ bp,
                                              float* __restrict__ a2out, float* __restrict__ pooled2) {
  __shared__ float lgS[128];
  int t = threadIdx.x, lane = t & 63, wave = t >> 6;
  int b = blockIdx.x;
  for (int i = 0; i < 32; ++i) {
    int row = wave * 32 + i;
    const float* xp = x + (size_t)(b * 128 + row) * 512;
    float acc = 0.f;
#pragma unroll
    for (int j = 0; j < 8; ++j) acc += xp[lane + 64 * j] * wp[lane + 64 * j];
#pragma unroll
    for (int d = 1; d < 64; d <<= 1) acc += __shfl_xor(acc, d);
    if (lane == 0) lgS[row] = acc + bp[0];
  }
  __syncthreads();
  if (wave == 0) {
    float a0 = lgS[lane], a1 = lgS[64 + lane];
    float m = fmaxf(a0, a1);
#pragma unroll
    for (int d = 1; d < 64; d <<= 1) m = fmaxf(m, __shfl_xor(m, d));
    float e0 = __expf(a0 - m), e1 = __expf(a1 - m);
    float sden = e0 + e1;
#pragma unroll
    for (int d = 1; d < 64; d <<= 1) sden += __shfl_xor(sden, d);
    a0 = e0 / sden; a1 = e1 / sden;
    lgS[lane] = a0; lgS[64 + lane] = a1;
    a2out[b * 128 + lane] = a0;
    a2out[b * 128 + 64 + lane] = a1;
  }
  __syncthreads();
  float acc0 = 0.f, acc1 = 0.f;
#pragma unroll 4
  for (int row = 0; row < 128; ++row) {
    float av = lgS[row];
    const float* xp = x + (size_t)(b * 128 + row) * 512;
    acc0 += av * xp[t];
    acc1 += av * xp[t + 256];
  }
  pooled2[(size_t)b * 512 + t] = acc0;
  pooled2[(size_t)b * 512 + t + 256] = acc1;
}

// ---------------- head ----------------
__global__ __launch_bounds__(256) void kemb(const float* __restrict__ pp, const float* __restrict__ pooled2,
                                            float* __restrict__ embo, float* __restrict__ embws) {
  __shared__ float red[256];
  int t = threadIdx.x, b = blockIdx.x;
  float pre[4];
#pragma unroll
  for (int qq = 0; qq < 4; ++qq) {
    int c = qq * 256 + t;
    float s;
    if (c < 512) {
      s = 0.f;
      for (int lsl = 0; lsl < 8; ++lsl) s += pp[(size_t)(b * 8 + lsl) * 512 + c];
    } else {
      s = pooled2[(size_t)b * 512 + (c - 512)];
    }
    pre[qq] = s;
  }
  float ssq = pre[0] * pre[0] + pre[1] * pre[1] + pre[2] * pre[2] + pre[3] * pre[3];
  red[t] = ssq; __syncthreads();
  for (int s2 = 128; s2 > 0; s2 >>= 1) { if (t < s2) red[t] += red[t + s2]; __syncthreads(); }
  float inv = 1.f / fmaxf(sqrtf(red[0]), 1e-12f);
#pragma unroll
  for (int qq = 0; qq < 4; ++qq) {
    int c = qq * 256 + t;
    float e = pre[qq] * inv;
    embo[(size_t)b * 1024 + c] = e;
    embws[(size_t)b * 1024 + c] = e;
  }
}

__global__ __launch_bounds__(256) void kmlp(const float* __restrict__ in, const float* __restrict__ W,
                                            const float* __restrict__ bias, float* __restrict__ out,
                                            int IN, int ON) {
  __shared__ float e[1024];
  int t = threadIdx.x;
  int chunks = ON >> 8;
  int b = blockIdx.x / chunks, jc = blockIdx.x % chunks;
  for (int q = t; q < IN; q += 256) e[q] = in[(size_t)b * IN + q];
  __syncthreads();
  int j = jc * 256 + t;
  float acc = bias[j];
#pragma unroll 8
  for (int i = 0; i < IN; ++i) acc += e[i] * W[(size_t)i * ON + j];
  out[(size_t)b * ON + j] = fmaxf(acc, 0.f);
}

__global__ void kout(const float* __restrict__ h2, const float* __restrict__ W3, const float* __restrict__ b3,
                     float* __restrict__ outp) {
  int b = blockIdx.x, lane = threadIdx.x;
  float acc = 0.f;
#pragma unroll
  for (int j = 0; j < 8; ++j) acc += h2[(size_t)b * 512 + lane + 64 * j] * W3[lane + 64 * j];
#pragma unroll
  for (int d = 1; d < 64; d <<= 1) acc += __shfl_xor(acc, d);
  if (lane == 0) outp[b] = acc + b3[0];
}

// ---------------- launch ----------------
extern "C" void kernel_launch(void* const* d_in, const int* in_sizes, int n_in,
                              void* d_out, int out_size, void* d_ws, size_t ws_size,
                              hipStream_t stream) {
  const float* seqs = (const float*)d_in[0];
  const float* smis = (const float*)d_in[1];
  const float* Wq = (const float*)d_in[2];
  const float* bq = (const float*)d_in[3];
  const float* Wk = (const float*)d_in[4];
  const float* bk = (const float*)d_in[5];
  const float* Wv = (const float*)d_in[6];
  const float* bv = (const float*)d_in[7];
  const float* wp = (const float*)d_in[8];
  const float* bp = (const float*)d_in[9];
  const float* W1 = (const float*)d_in[10];
  const float* b1 = (const float*)d_in[11];
  const float* W2 = (const float*)d_in[12];
  const float* b2 = (const float*)d_in[13];
  const float* W3 = (const float*)d_in[14];
  const float* b3 = (const float*)d_in[15];
  float* out = (float*)d_out;
  char* ws = (char*)d_ws;

  float* nrm_s = (float*)(ws + WS_NRM_S);
  float* nrm_m = (float*)(ws + WS_NRM_M);
  float* part_s = (float*)(ws + WS_PART);
  float* part_m = (float*)(ws + WS_PARTM);
  float* bcat = (float*)(ws + WS_BCAT);
  float* log1 = (float*)(ws + WS_LOG1);
  float* pp1 = (float*)(ws + WS_PP1);
  float* pooled2 = (float*)(ws + WS_POOL2);
  float* embws = (float*)(ws + WS_EMB);
  float* h1 = (float*)(ws + WS_H1);
  float* h2 = (float*)(ws + WS_H2);
  unsigned short* wct = (unsigned short*)(ws + WS_WCT);
  unsigned short* smis_nb = (unsigned short*)(ws + WS_SMISNB);
  unsigned short* Psmis = (unsigned short*)(ws + WS_PSMIS);
  float* seqs_out = (float*)(ws + WS_SEQSOUT);
  unsigned short* seqs_nb = (unsigned short*)(ws + WS_SEQSNB);
  unsigned short* Pseqs = (unsigned short*)(ws + WS_PSEQS);
  unsigned short* smil = (unsigned short*)(ws + WS_SMILOUT);
  unsigned short* S2 = (unsigned short*)(ws + WS_S2);

  // 1. column norms
  knorm_part<<<dim3(8, 2, 16), 256, 0, stream>>>(seqs, part_s, 2048, 256, 8);
  knorm_part<<<dim3(1, 2, 16), 256, 0, stream>>>(smis, part_m, 128, 128, 1);
  knorm_fin<<<dim3(32), 256, 0, stream>>>(part_s, nrm_s, 8);
  knorm_fin<<<dim3(32), 256, 0, stream>>>(part_m, nrm_m, 1);
  // 2. normalize + cast to bf16
  kcast<<<dim3(16384), 256, 0, stream>>>(seqs, nrm_s, seqs_nb, 20, 16 * 2048 * 512);
  kcast<<<dim3(1024), 256, 0, stream>>>(smis, nrm_m, smis_nb, 16, 16 * 128 * 512);
  // 3. weight prep
  kprepw<<<dim3(16, 16, 3), 256, 0, stream>>>(Wq, Wk, Wv, wct);
  kprepb<<<dim3(6), 256, 0, stream>>>(bq, bk, bv, bcat);
  // 4. fused QKV projections
  kgemm<<<dim3(12, 256), 256, 0, stream>>>(seqs_nb, wct, bcat, Pseqs, 512, NC);
  kgemm<<<dim3(12, 16), 256, 0, stream>>>(smis_nb, wct, bcat, Psmis, 512, NC);
  // 5. fusion 1 attention (writes smil, aliases dead seqs_nb)
  kfusion1<<<dim3(32, 8, 16), 256, 0, stream>>>(Pseqs, Psmis, smil);
  // 6. pool 1
  kpool1a<<<dim3(8192), 256, 0, stream>>>(smil, wp, bp, log1);
  kpool1b<<<dim3(128), 256, 0, stream>>>(smil, log1, out + OUT_A1, pp1);
  // 7. fusion 2
  kf2scores<<<dim3(16, 128), 256, 0, stream>>>(Psmis, Pseqs, S2);
  kf2select<<<dim3(1024), 256, 0, stream>>>(S2, Pseqs, seqs_out);
  kpool2<<<dim3(16), 256, 0, stream>>>(seqs_out, wp, bp, out + OUT_A2, pooled2);
  // 8. head
  kemb<<<dim3(16), 256, 0, stream>>>(pp1, pooled2, out + OUT_EMB, embws);
  kmlp<<<dim3(64), 256, 0, stream>>>(embws, W1, b1, h1, 1024, 1024);
  kmlp<<<dim3(32), 256, 0, stream>>>(h1, W2, b2, h2, 1024, 512);
  kout<<<dim3(16), 64, 0, stream>>>(h2, W3, b3, out + OUT_OUT);
}

// Round 2
// 949.287 us; speedup vs baseline: 1.2836x; 1.2836x over previous
//
#include <hip/hip_runtime.h>
#include <cfloat>
#include <cstdint>

// ---------------- problem constants ----------------
#define NC 1536   // 3*H concatenated projection width

// d_out float offsets: emb[16,1024] | out[16] | smiles_attn_pool[16,2048] | seqs_attn_pool[16,128]
#define OUT_EMB 0
#define OUT_OUT 16384
#define OUT_A1  16400
#define OUT_A2  49168

// ws byte offsets
#define WS_NRM_S   0u
#define WS_NRM_M   32768u
#define WS_PART    65536u
#define WS_PARTM   327680u
#define WS_BCAT    360448u
#define WS_LOG1    366592u
#define WS_PP1     505856u
#define WS_POOL2   768000u
#define WS_EMB     800768u
#define WS_H1      866304u
#define WS_H2      931840u
#define WS_WCT     1048576u
#define WS_SMISNB  2621440u
#define WS_PSMIS   4718592u
#define WS_SEQSOUT 11010048u
#define WS_SEQSNB  15204352u
#define WS_PSEQS   48758784u
#define WS_SMILOUT WS_SEQSNB          // seqs_nb dead after GEMM1; reuse for smiles_out
#define WS_S2      149422080u          // ws total need ~216.5 MB

typedef float f32x4 __attribute__((ext_vector_type(4)));
typedef __bf16 bf16x8 __attribute__((ext_vector_type(8)));
typedef unsigned short u16x8 __attribute__((ext_vector_type(8)));

__device__ __forceinline__ float bf2f(unsigned short h) {
  return __uint_as_float(((unsigned int)h) << 16);
}
__device__ __forceinline__ unsigned short f2bf(float f) {
  unsigned int u = __float_as_uint(f);
  return (unsigned short)((u + 0x7FFFu + ((u >> 16) & 1u)) >> 16);
}
__device__ __forceinline__ void gld16(const unsigned short* g, unsigned short* l) {
  __builtin_amdgcn_global_load_lds(
      (__attribute__((address_space(1))) unsigned int*)(uintptr_t)g,
      (__attribute__((address_space(3))) unsigned int*)l, 16, 0, 0);
}

// ---------------- column-wise l2 norms (axis=1) ----------------
__global__ __launch_bounds__(256) void knorm_part(const float* __restrict__ x, float* __restrict__ part,
                                                  int L, int SL, int NS) {
  int ls = blockIdx.x, hc = blockIdx.y, b = blockIdx.z, t = threadIdx.x;
  int h = hc * 256 + t;
  const float* xp = x + (size_t)b * L * 512 + h;
  float acc = 0.f;
  int l0 = ls * SL;
  for (int l = 0; l < SL; ++l) {
    float v = xp[(size_t)(l0 + l) * 512];
    acc += v * v;
  }
  part[(((size_t)b * 2 + hc) * NS + ls) * 256 + t] = acc;
}

__global__ __launch_bounds__(256) void knorm_fin(const float* __restrict__ part, float* __restrict__ inv, int NS) {
  int bh = blockIdx.x, t = threadIdx.x;
  float s = 0.f;
  for (int j = 0; j < NS; ++j) s += part[((size_t)bh * NS + j) * 256 + t];
  inv[(size_t)bh * 256 + t] = 1.f / fmaxf(sqrtf(s), 1e-12f);
}

__global__ __launch_bounds__(256) void kcast(const float* __restrict__ x, const float* __restrict__ inv,
                                             unsigned short* __restrict__ o, int shiftB, int total) {
  int i4 = (blockIdx.x * 256 + threadIdx.x) * 4;
  if (i4 >= total) return;
  int b = i4 >> shiftB;
  float4 v = *(const float4*)(x + i4);
  float4 nv = *(const float4*)(inv + (b << 9) + (i4 & 511));
  ushort4 r;
  r.x = f2bf(v.x * nv.x); r.y = f2bf(v.y * nv.y);
  r.z = f2bf(v.z * nv.z); r.w = f2bf(v.w * nv.w);
  *(ushort4*)(o + i4) = r;
}

// ---------------- weight prep: WcatT[1536][512] bf16 (B^T layout), bcat ----------------
__global__ __launch_bounds__(256) void kprepw(const float* __restrict__ Wq, const float* __restrict__ Wk,
                                              const float* __restrict__ Wv, unsigned short* __restrict__ WT) {
  __shared__ float T[32][33];
  int ti = blockIdx.x, tj = blockIdx.y, m = blockIdx.z;
  const float* W = m == 0 ? Wq : (m == 1 ? Wk : Wv);
  int c = threadIdx.x & 31, r0 = threadIdx.x >> 5;
#pragma unroll
  for (int j = 0; j < 4; ++j) {
    int r = r0 + j * 8;
    T[r][c] = W[(size_t)(ti * 32 + r) * 512 + tj * 32 + c];
  }
  __syncthreads();
#pragma unroll
  for (int j = 0; j < 4; ++j) {
    int r = r0 + j * 8;
    WT[(size_t)(m * 512 + tj * 32 + r) * 512 + ti * 32 + c] = f2bf(T[c][r]);
  }
}

__global__ void kprepb(const float* bq, const float* bk, const float* bv, float* bcat) {
  int i = blockIdx.x * 256 + threadIdx.x;
  if (i >= 1536) return;
  bcat[i] = i < 512 ? bq[i] : (i < 1024 ? bk[i - 512] : bv[i - 1024]);
}

// ---------------- bf16 MFMA GEMM: C[M,N] = A[M,K] @ Bt[N,K]^T + bias ----------------
__global__ __launch_bounds__(256) void kgemm(const unsigned short* __restrict__ A,
                                             const unsigned short* __restrict__ Bt,
                                             const float* __restrict__ bias,
                                             unsigned short* __restrict__ C,
                                             int K, int N) {
  __shared__ unsigned short As[128 * 32], Bs[128 * 32];
  int tid = threadIdx.x, lane = tid & 63, wave = tid >> 6;
  int m0 = blockIdx.y * 128, n0 = blockIdx.x * 128;
  f32x4 acc[4][4] = {};
  int wm = (wave >> 1) * 64, wn = (wave & 1) * 64;
  int frow = lane & 15, fk = (lane >> 4) * 8;
  for (int k0 = 0; k0 < K; k0 += 32) {
    if (k0) __syncthreads();
#pragma unroll
    for (int j = 0; j < 2; ++j) {
      int ch = j * 256 + tid;
      int row = ch >> 2, kc = (ch & 3) * 8;
      gld16(A + (size_t)(m0 + row) * K + k0 + kc, As + ch * 8);
      gld16(Bt + (size_t)(n0 + row) * K + k0 + kc, Bs + ch * 8);
    }
    __syncthreads();
    bf16x8 af[4], bfv[4];
#pragma unroll
    for (int mt = 0; mt < 4; ++mt) af[mt] = *(const bf16x8*)&As[(wm + mt * 16 + frow) * 32 + fk];
#pragma unroll
    for (int nt = 0; nt < 4; ++nt) bfv[nt] = *(const bf16x8*)&Bs[(wn + nt * 16 + frow) * 32 + fk];
#pragma unroll
    for (int mt = 0; mt < 4; ++mt)
#pragma unroll
      for (int nt = 0; nt < 4; ++nt)
        acc[mt][nt] = __builtin_amdgcn_mfma_f32_16x16x32_bf16(af[mt], bfv[nt], acc[mt][nt], 0, 0, 0);
  }
  int q = lane >> 4, c15 = lane & 15;
#pragma unroll
  for (int mt = 0; mt < 4; ++mt)
#pragma unroll
    for (int nt = 0; nt < 4; ++nt) {
      int col = n0 + wn + nt * 16 + c15;
      float bv = bias ? bias[col] : 0.f;
#pragma unroll
      for (int r = 0; r < 4; ++r) {
        int row = m0 + wm + mt * 16 + q * 4 + r;
        C[(size_t)row * N + col] = f2bf(acc[mt][nt][r] + bv);
      }
    }
}

// ---------------- fusion 1: Q=seqs(2048) K,V=smis(128); top-32 of 128 ----------------
// radix-select over ballots (exact, lax.top_k stable tie-break) + MFMA for P@V
__global__ __launch_bounds__(256) void kfusion1(const unsigned short* __restrict__ Pseqs,
                                                const unsigned short* __restrict__ Psmis,
                                                unsigned short* __restrict__ smil) {
  constexpr int PP = 136;                 // halfword pitch, rows 16B-aligned
  __shared__ unsigned short Sc[64 * PP];  // scores, then P (bf16)
  __shared__ unsigned short Vt[64 * PP];  // V^T [e][s]
  int tid = threadIdx.x, lane = tid & 63, w = tid >> 6;
  int lt = blockIdx.x, h = blockIdx.y, b = blockIdx.z;
  int l0 = lt * 64;
  int frow = lane & 15, q = lane >> 4, fk8 = q * 8;

  // stage V^T (coalesced global read, transposed LDS write; one-time cost)
  for (int ch = tid; ch < 1024; ch += 256) {
    int s = ch >> 3, e8 = (ch & 7) * 8;
    u16x8 vv = *(const u16x8*)&Psmis[(size_t)(b * 128 + s) * NC + 1024 + h * 64 + e8];
#pragma unroll
    for (int j = 0; j < 8; ++j) Vt[(e8 + j) * PP + s] = vv[j];
  }

  // scores: this wave's 16 Q-rows x 128 keys, fragments straight from global (L2-hot)
  {
    f32x4 acc[8] = {};
    const unsigned short* qrow = Pseqs + (size_t)(b * 2048 + l0 + w * 16 + frow) * NC + h * 64 + fk8;
#pragma unroll
    for (int ks = 0; ks < 2; ++ks) {
      bf16x8 a = *(const bf16x8*)(qrow + ks * 32);
#pragma unroll
      for (int nt = 0; nt < 8; ++nt) {
        bf16x8 bb = *(const bf16x8*)&Psmis[(size_t)(b * 128 + nt * 16 + frow) * NC + 512 + h * 64 + ks * 32 + fk8];
        acc[nt] = __builtin_amdgcn_mfma_f32_16x16x32_bf16(a, bb, acc[nt], 0, 0, 0);
      }
    }
#pragma unroll
    for (int nt = 0; nt < 8; ++nt)
#pragma unroll
      for (int r = 0; r < 4; ++r)
        Sc[(w * 16 + q * 4 + r) * PP + nt * 16 + frow] = f2bf(acc[nt][r]);
  }

  // per-row exact top-32 of 128 via 16-bit radix select on ballots, then softmax -> P
  uint64_t lmask = (1ull << lane) - 1ull;
  for (int i = 0; i < 16; ++i) {
    int off = (w * 16 + i) * PP;
    unsigned h0 = Sc[off + lane], h1 = Sc[off + 64 + lane];
    // monotone unsigned transform of bf16 bits
    unsigned t0 = (h0 & 0x8000u) ? (h0 ^ 0xFFFFu) : (h0 | 0x8000u);
    unsigned t1 = (h1 & 0x8000u) ? (h1 ^ 0xFFFFu) : (h1 | 0x8000u);
    unsigned act0 = 1u, act1 = 1u, Tv = 0u;
    int rem = 32;
#pragma unroll
    for (int bit = 15; bit >= 0; --bit) {
      unsigned b0 = act0 & (t0 >> bit);   // act in {0,1} => result is act && bit
      unsigned b1 = act1 & (t1 >> bit);
      int cnt = __popcll(__ballot((int)b0)) + __popcll(__ballot((int)b1));
      bool take = cnt >= rem;             // wave-uniform
      act0 = take ? b0 : (act0 ^ b0);
      act1 = take ? b1 : (act1 ^ b1);
      rem = take ? rem : rem - cnt;
      Tv = take ? (Tv | (1u << bit)) : Tv;
    }
    // ties (t == Tv): pick lowest original index first (stable like lax.top_k)
    uint64_t m0 = __ballot((int)act0), m1 = __ballot((int)act1);
    int pre0 = __popcll(m0 & lmask);
    int pre1 = __popcll(m0) + __popcll(m1 & lmask);
    int sel0 = (t0 > Tv) || (act0 && pre0 < rem);
    int sel1 = (t1 > Tv) || (act1 && pre1 < rem);
    unsigned hT = (Tv & 0x8000u) ? (Tv ^ 0x8000u) : (Tv ^ 0xFFFFu);
    float vT = bf2f((unsigned short)hT);  // min selected value: exponents in [0, tiny]
    float p0 = sel0 ? __expf((bf2f((unsigned short)h0) - vT) * 0.125f) : 0.f;
    float p1 = sel1 ? __expf((bf2f((unsigned short)h1) - vT) * 0.125f) : 0.f;
    float den = p0 + p1;
#pragma unroll
    for (int d = 1; d < 64; d <<= 1) den += __shfl_xor(den, d);
    float inv = 1.f / den;
    Sc[off + lane] = f2bf(p0 * inv);
    Sc[off + 64 + lane] = f2bf(p1 * inv);
  }
  __syncthreads();  // Vt (block-wide) + P ready

  // O = P[64x128] @ V[128x64] via MFMA (A = P rows, B = Vt rows)
  f32x4 oacc[4] = {};
#pragma unroll
  for (int k0 = 0; k0 < 128; k0 += 32) {
    bf16x8 a = *(const bf16x8*)&Sc[(w * 16 + frow) * PP + k0 + fk8];
#pragma unroll
    for (int nt = 0; nt < 4; ++nt) {
      bf16x8 bb = *(const bf16x8*)&Vt[(nt * 16 + frow) * PP + k0 + fk8];
      oacc[nt] = __builtin_amdgcn_mfma_f32_16x16x32_bf16(a, bb, oacc[nt], 0, 0, 0);
    }
  }
#pragma unroll
  for (int nt = 0; nt < 4; ++nt)
#pragma unroll
    for (int r = 0; r < 4; ++r)
      smil[(size_t)(b * 2048 + l0 + w * 16 + q * 4 + r) * 512 + h * 64 + nt * 16 + frow] = f2bf(oacc[nt][r]);
}

// ---------------- fusion 2 scores: S2[bh][l 128][s 2048] bf16 ----------------
__global__ __launch_bounds__(256) void kf2scores(const unsigned short* __restrict__ Psmis,
                                                 const unsigned short* __restrict__ Pseqs,
                                                 unsigned short* __restrict__ S2) {
  __shared__ unsigned short As[128 * 32], Bs[128 * 32];
  int tid = threadIdx.x, lane = tid & 63, wave = tid >> 6;
  int st = blockIdx.x, bh = blockIdx.y;
  int b = bh >> 3, h = bh & 7;
  int s0 = st * 128;
  const unsigned short* Abase = Psmis + (size_t)b * 128 * NC + h * 64;
  const unsigned short* Bbase = Pseqs + (size_t)b * 2048 * NC + 512 + h * 64;
  f32x4 acc[4][4] = {};
  int wm = (wave >> 1) * 64, wn = (wave & 1) * 64;
  int frow = lane & 15, fk = (lane >> 4) * 8;
  for (int k0 = 0; k0 < 64; k0 += 32) {
    if (k0) __syncthreads();
#pragma unroll
    for (int j = 0; j < 2; ++j) {
      int ch = j * 256 + tid;
      int row = ch >> 2, kc = (ch & 3) * 8;
      gld16(Abase + (size_t)row * NC + k0 + kc, As + ch * 8);
      gld16(Bbase + (size_t)(s0 + row) * NC + k0 + kc, Bs + ch * 8);
    }
    __syncthreads();
    bf16x8 af[4], bfv[4];
#pragma unroll
    for (int mt = 0; mt < 4; ++mt) af[mt] = *(const bf16x8*)&As[(wm + mt * 16 + frow) * 32 + fk];
#pragma unroll
    for (int nt = 0; nt < 4; ++nt) bfv[nt] = *(const bf16x8*)&Bs[(wn + nt * 16 + frow) * 32 + fk];
#pragma unroll
    for (int mt = 0; mt < 4; ++mt)
#pragma unroll
      for (int nt = 0; nt < 4; ++nt)
        acc[mt][nt] = __builtin_amdgcn_mfma_f32_16x16x32_bf16(af[mt], bfv[nt], acc[mt][nt], 0, 0, 0);
  }
  int q = lane >> 4, c15 = lane & 15;
  unsigned short* outp = S2 + (size_t)bh * 128 * 2048;
#pragma unroll
  for (int mt = 0; mt < 4; ++mt)
#pragma unroll
    for (int nt = 0; nt < 4; ++nt)
#pragma unroll
      for (int r = 0; r < 4; ++r)
        outp[(size_t)(wm + mt * 16 + q * 4 + r) * 2048 + s0 + wn + nt * 16 + c15] = f2bf(acc[mt][nt][r]);
}

// ---------------- fusion 2 select: top-32 of 2048 per row + softmax + AV ----------------
__global__ __launch_bounds__(256) void kf2select(const unsigned short* __restrict__ S2,
                                                 const unsigned short* __restrict__ Pseqs,
                                                 float* __restrict__ seqs_out) {
  int tid = threadIdx.x, lane = tid & 63, wave = tid >> 6;
  for (int i = 0; i < 4; ++i) {
    int rid = blockIdx.x * 16 + wave * 4 + i;
    int l = rid & 127, bh = rid >> 7;
    int h = bh & 7, b = bh >> 3;
    const unsigned short* rowp = S2 + (size_t)rid * 2048;
    float v[32];
#pragma unroll
    for (int j = 0; j < 32; j += 8) {
      uint4 pk = *(const uint4*)&rowp[lane * 32 + j];
      v[j + 0] = bf2f((unsigned short)(pk.x & 0xFFFFu)); v[j + 1] = bf2f((unsigned short)(pk.x >> 16));
      v[j + 2] = bf2f((unsigned short)(pk.y & 0xFFFFu)); v[j + 3] = bf2f((unsigned short)(pk.y >> 16));
      v[j + 4] = bf2f((unsigned short)(pk.z & 0xFFFFu)); v[j + 5] = bf2f((unsigned short)(pk.z >> 16));
      v[j + 6] = bf2f((unsigned short)(pk.w & 0xFFFFu)); v[j + 7] = bf2f((unsigned short)(pk.w >> 16));
    }
    float lm = -FLT_MAX; int li = 0;
#pragma unroll
    for (int j = 0; j < 32; ++j) if (v[j] > lm) { lm = v[j]; li = j; }
    float pv = 0.f; int ps = 0;
    for (int t = 0; t < 32; ++t) {
      float bvv = lm; unsigned int bs = (unsigned int)(lane * 32 + li);
#pragma unroll
      for (int d = 32; d; d >>= 1) {
        float ov = __shfl_xor(bvv, d);
        unsigned int os = (unsigned int)__shfl_xor((int)bs, d);
        if (ov > bvv || (ov == bvv && os < bs)) { bvv = ov; bs = os; }
      }
      if (lane == t) { pv = bvv; ps = (int)bs; }
      if ((int)(bs >> 5) == lane) {
        int rj = (int)(bs & 31u);
        lm = -FLT_MAX; li = 0;
#pragma unroll
        for (int j = 0; j < 32; ++j) {
          if (j == rj) v[j] = -FLT_MAX;
          if (v[j] > lm) { lm = v[j]; li = j; }
        }
      }
    }
    float mxv = __shfl(pv, 0);
    float p = (lane < 32) ? __expf((pv - mxv) * 0.125f) : 0.f;
    float den = p;
#pragma unroll
    for (int d = 1; d < 64; d <<= 1) den += __shfl_xor(den, d);
    p /= den;
    float outv = 0.f;
#pragma unroll
    for (int t = 0; t < 32; ++t) {
      float pt = __shfl(p, t);
      int stt = __shfl(ps, t);
      outv += pt * bf2f(Pseqs[(size_t)(b * 2048 + stt) * NC + 1024 + h * 64 + lane]);
    }
    seqs_out[(size_t)(b * 128 + l) * 512 + h * 64 + lane] = outv;
  }
}

// ---------------- pooling ----------------
__device__ __forceinline__ float dot8(uint4 pk, const float* w) {
  float s = bf2f((unsigned short)(pk.x & 0xFFFFu)) * w[0] + bf2f((unsigned short)(pk.x >> 16)) * w[1];
  s += bf2f((unsigned short)(pk.y & 0xFFFFu)) * w[2] + bf2f((unsigned short)(pk.y >> 16)) * w[3];
  s += bf2f((unsigned short)(pk.z & 0xFFFFu)) * w[4] + bf2f((unsigned short)(pk.z >> 16)) * w[5];
  s += bf2f((unsigned short)(pk.w & 0xFFFFu)) * w[6] + bf2f((unsigned short)(pk.w >> 16)) * w[7];
  return s;
}

__global__ __launch_bounds__(256) void kpool1a(const unsigned short* __restrict__ x,
                                               const float* __restrict__ wp, const float* __restrict__ bp,
                                               float* __restrict__ logits) {
  int tid = threadIdx.x, lane = tid & 63, wave = tid >> 6;
  int r = blockIdx.x * 4 + wave;
  uint4 pk = *(const uint4*)(x + (size_t)r * 512 + lane * 8);
  float acc = dot8(pk, wp + lane * 8);
#pragma unroll
  for (int d = 1; d < 64; d <<= 1) acc += __shfl_xor(acc, d);
  if (lane == 0) logits[r] = acc + bp[0];
}

__global__ __launch_bounds__(256) void kpool1b(const unsigned short* __restrict__ x,
                                               const float* __restrict__ logits,
                                               float* __restrict__ aout, float* __restrict__ pp) {
  __shared__ float red[256];
  __shared__ float aS[256];
  int t = threadIdx.x;
  int b = blockIdx.x >> 3, ls = blockIdx.x & 7;
  const float* lg = logits + b * 2048;
  float lm = -FLT_MAX;
  for (int j = t; j < 2048; j += 256) lm = fmaxf(lm, lg[j]);
  red[t] = lm; __syncthreads();
  for (int s = 128; s > 0; s >>= 1) { if (t < s) red[t] = fmaxf(red[t], red[t + s]); __syncthreads(); }
  float M = red[0]; __syncthreads();
  float sm = 0.f;
  for (int j = t; j < 2048; j += 256) sm += __expf(lg[j] - M);
  red[t] = sm; __syncthreads();
  for (int s = 128; s > 0; s >>= 1) { if (t < s) red[t] += red[t + s]; __syncthreads(); }
  float D = red[0];
  int l0 = ls * 256;
  float a = __expf(lg[l0 + t] - M) / D;
  aS[t] = a;
  aout[b * 2048 + l0 + t] = a;
  __syncthreads();
  float acc0 = 0.f, acc1 = 0.f;
  const unsigned short* xb = x + ((size_t)b * 2048 + l0) * 512;
#pragma unroll 4
  for (int ll = 0; ll < 256; ++ll) {
    float av = aS[ll];
    acc0 += av * bf2f(xb[(size_t)ll * 512 + t]);
    acc1 += av * bf2f(xb[(size_t)ll * 512 + t + 256]);
  }
  pp[(size_t)(b * 8 + ls) * 512 + t] = acc0;
  pp[(size_t)(b * 8 + ls) * 512 + t + 256] = acc1;
}

__global__ __launch_bounds__(256) void kpool2(const float* __restrict__ x,
                                              const float* __restrict__ wp, const float* __restrict__ bp,
                                              float* __restrict__ a2out, float* __restrict__ pooled2) {
  __shared__ float lgS[128];
  int t = threadIdx.x, lane = t & 63, wave = t >> 6;
  int b = blockIdx.x;
  for (int i = 0; i < 32; ++i) {
    int row = wave * 32 + i;
    const float* xp = x + (size_t)(b * 128 + row) * 512;
    float acc = 0.f;
#pragma unroll
    for (int j = 0; j < 8; ++j) acc += xp[lane + 64 * j] * wp[lane + 64 * j];
#pragma unroll
    for (int d = 1; d < 64; d <<= 1) acc += __shfl_xor(acc, d);
    if (lane == 0) lgS[row] = acc + bp[0];
  }
  __syncthreads();
  if (wave == 0) {
    float a0 = lgS[lane], a1 = lgS[64 + lane];
    float m = fmaxf(a0, a1);
#pragma unroll
    for (int d = 1; d < 64; d <<= 1) m = fmaxf(m, __shfl_xor(m, d));
    float e0 = __expf(a0 - m), e1 = __expf(a1 - m);
    float sden = e0 + e1;
#pragma unroll
    for (int d = 1; d < 64; d <<= 1) sden += __shfl_xor(sden, d);
    a0 = e0 / sden; a1 = e1 / sden;
    lgS[lane] = a0; lgS[64 + lane] = a1;
    a2out[b * 128 + lane] = a0;
    a2out[b * 128 + 64 + lane] = a1;
  }
  __syncthreads();
  float acc0 = 0.f, acc1 = 0.f;
#pragma unroll 4
  for (int row = 0; row < 128; ++row) {
    float av = lgS[row];
    const float* xp = x + (size_t)(b * 128 + row) * 512;
    acc0 += av * xp[t];
    acc1 += av * xp[t + 256];
  }
  pooled2[(size_t)b * 512 + t] = acc0;
  pooled2[(size_t)b * 512 + t + 256] = acc1;
}

// ---------------- head ----------------
__global__ __launch_bounds__(256) void kemb(const float* __restrict__ pp, const float* __restrict__ pooled2,
                                            float* __restrict__ embo, float* __restrict__ embws) {
  __shared__ float red[256];
  int t = threadIdx.x, b = blockIdx.x;
  float pre[4];
#pragma unroll
  for (int qq = 0; qq < 4; ++qq) {
    int c = qq * 256 + t;
    float s;
    if (c < 512) {
      s = 0.f;
      for (int lsl = 0; lsl < 8; ++lsl) s += pp[(size_t)(b * 8 + lsl) * 512 + c];
    } else {
      s = pooled2[(size_t)b * 512 + (c - 512)];
    }
    pre[qq] = s;
  }
  float ssq = pre[0] * pre[0] + pre[1] * pre[1] + pre[2] * pre[2] + pre[3] * pre[3];
  red[t] = ssq; __syncthreads();
  for (int s2 = 128; s2 > 0; s2 >>= 1) { if (t < s2) red[t] += red[t + s2]; __syncthreads(); }
  float inv = 1.f / fmaxf(sqrtf(red[0]), 1e-12f);
#pragma unroll
  for (int qq = 0; qq < 4; ++qq) {
    int c = qq * 256 + t;
    float e = pre[qq] * inv;
    embo[(size_t)b * 1024 + c] = e;
    embws[(size_t)b * 1024 + c] = e;
  }
}

__global__ __launch_bounds__(256) void kmlp(const float* __restrict__ in, const float* __restrict__ W,
                                            const float* __restrict__ bias, float* __restrict__ out,
                                            int IN, int ON) {
  __shared__ float e[1024];
  int t = threadIdx.x;
  int chunks = ON >> 8;
  int b = blockIdx.x / chunks, jc = blockIdx.x % chunks;
  for (int q = t; q < IN; q += 256) e[q] = in[(size_t)b * IN + q];
  __syncthreads();
  int j = jc * 256 + t;
  float acc = bias[j];
#pragma unroll 8
  for (int i = 0; i < IN; ++i) acc += e[i] * W[(size_t)i * ON + j];
  out[(size_t)b * ON + j] = fmaxf(acc, 0.f);
}

__global__ void kout(const float* __restrict__ h2, const float* __restrict__ W3, const float* __restrict__ b3,
                     float* __restrict__ outp) {
  int b = blockIdx.x, lane = threadIdx.x;
  float acc = 0.f;
#pragma unroll
  for (int j = 0; j < 8; ++j) acc += h2[(size_t)b * 512 + lane + 64 * j] * W3[lane + 64 * j];
#pragma unroll
  for (int d = 1; d < 64; d <<= 1) acc += __shfl_xor(acc, d);
  if (lane == 0) outp[b] = acc + b3[0];
}

// ---------------- launch ----------------
extern "C" void kernel_launch(void* const* d_in, const int* in_sizes, int n_in,
                              void* d_out, int out_size, void* d_ws, size_t ws_size,
                              hipStream_t stream) {
  const float* seqs = (const float*)d_in[0];
  const float* smis = (const float*)d_in[1];
  const float* Wq = (const float*)d_in[2];
  const float* bq = (const float*)d_in[3];
  const float* Wk = (const float*)d_in[4];
  const float* bk = (const float*)d_in[5];
  const float* Wv = (const float*)d_in[6];
  const float* bv = (const float*)d_in[7];
  const float* wp = (const float*)d_in[8];
  const float* bp = (const float*)d_in[9];
  const float* W1 = (const float*)d_in[10];
  const float* b1 = (const float*)d_in[11];
  const float* W2 = (const float*)d_in[12];
  const float* b2 = (const float*)d_in[13];
  const float* W3 = (const float*)d_in[14];
  const float* b3 = (const float*)d_in[15];
  float* out = (float*)d_out;
  char* ws = (char*)d_ws;

  float* nrm_s = (float*)(ws + WS_NRM_S);
  float* nrm_m = (float*)(ws + WS_NRM_M);
  float* part_s = (float*)(ws + WS_PART);
  float* part_m = (float*)(ws + WS_PARTM);
  float* bcat = (float*)(ws + WS_BCAT);
  float* log1 = (float*)(ws + WS_LOG1);
  float* pp1 = (float*)(ws + WS_PP1);
  float* pooled2 = (float*)(ws + WS_POOL2);
  float* embws = (float*)(ws + WS_EMB);
  float* h1 = (float*)(ws + WS_H1);
  float* h2 = (float*)(ws + WS_H2);
  unsigned short* wct = (unsigned short*)(ws + WS_WCT);
  unsigned short* smis_nb = (unsigned short*)(ws + WS_SMISNB);
  unsigned short* Psmis = (unsigned short*)(ws + WS_PSMIS);
  float* seqs_out = (float*)(ws + WS_SEQSOUT);
  unsigned short* seqs_nb = (unsigned short*)(ws + WS_SEQSNB);
  unsigned short* Pseqs = (unsigned short*)(ws + WS_PSEQS);
  unsigned short* smil = (unsigned short*)(ws + WS_SMILOUT);
  unsigned short* S2 = (unsigned short*)(ws + WS_S2);

  // 1. column norms
  knorm_part<<<dim3(8, 2, 16), 256, 0, stream>>>(seqs, part_s, 2048, 256, 8);
  knorm_part<<<dim3(1, 2, 16), 256, 0, stream>>>(smis, part_m, 128, 128, 1);
  knorm_fin<<<dim3(32), 256, 0, stream>>>(part_s, nrm_s, 8);
  knorm_fin<<<dim3(32), 256, 0, stream>>>(part_m, nrm_m, 1);
  // 2. normalize + cast to bf16
  kcast<<<dim3(16384), 256, 0, stream>>>(seqs, nrm_s, seqs_nb, 20, 16 * 2048 * 512);
  kcast<<<dim3(1024), 256, 0, stream>>>(smis, nrm_m, smis_nb, 16, 16 * 128 * 512);
  // 3. weight prep
  kprepw<<<dim3(16, 16, 3), 256, 0, stream>>>(Wq, Wk, Wv, wct);
  kprepb<<<dim3(6), 256, 0, stream>>>(bq, bk, bv, bcat);
  // 4. fused QKV projections
  kgemm<<<dim3(12, 256), 256, 0, stream>>>(seqs_nb, wct, bcat, Pseqs, 512, NC);
  kgemm<<<dim3(12, 16), 256, 0, stream>>>(smis_nb, wct, bcat, Psmis, 512, NC);
  // 5. fusion 1 attention (writes smil, aliases dead seqs_nb)
  kfusion1<<<dim3(32, 8, 16), 256, 0, stream>>>(Pseqs, Psmis, smil);
  // 6. pool 1
  kpool1a<<<dim3(8192), 256, 0, stream>>>(smil, wp, bp, log1);
  kpool1b<<<dim3(128), 256, 0, stream>>>(smil, log1, out + OUT_A1, pp1);
  // 7. fusion 2
  kf2scores<<<dim3(16, 128), 256, 0, stream>>>(Psmis, Pseqs, S2);
  kf2select<<<dim3(1024), 256, 0, stream>>>(S2, Pseqs, seqs_out);
  kpool2<<<dim3(16), 256, 0, stream>>>(seqs_out, wp, bp, out + OUT_A2, pooled2);
  // 8. head
  kemb<<<dim3(16), 256, 0, stream>>>(pp1, pooled2, out + OUT_EMB, embws);
  kmlp<<<dim3(64), 256, 0, stream>>>(embws, W1, b1, h1, 1024, 1024);
  kmlp<<<dim3(32), 256, 0, stream>>>(h1, W2, b2, h2, 1024, 512);
  kout<<<dim3(16), 64, 0, stream>>>(h2, W3, b3, out + OUT_OUT);
}

// Round 4
// 758.076 us; speedup vs baseline: 1.6074x; 1.2522x over previous
//
#include <hip/hip_runtime.h>
#include <cfloat>
#include <cstdint>

// ---------------- problem constants ----------------
#define NC 1536   // 3*H concatenated projection width

// d_out float offsets: emb[16,1024] | out[16] | smiles_attn_pool[16,2048] | seqs_attn_pool[16,128]
#define OUT_EMB 0
#define OUT_OUT 16384
#define OUT_A1  16400
#define OUT_A2  49168

// ws byte offsets
#define WS_NRM_S   0u
#define WS_NRM_M   32768u
#define WS_PART    65536u
#define WS_PARTM   327680u
#define WS_BCAT    360448u
#define WS_LOG1    366592u
#define WS_PP1     505856u
#define WS_POOL2   768000u
#define WS_EMB     800768u
#define WS_H1      866304u
#define WS_H2      931840u
#define WS_WCT     1048576u
#define WS_SMISNB  2621440u
#define WS_PSMIS   4718592u
#define WS_SEQSOUT 11010048u
#define WS_SEQSNB  15204352u
#define WS_PSEQS   48758784u
#define WS_SMILOUT WS_SEQSNB          // seqs_nb dead after GEMM1; reuse for smiles_out
#define WS_S2      149422080u          // ws total need ~216.5 MB

typedef float f32x4 __attribute__((ext_vector_type(4)));
typedef __bf16 bf16x8 __attribute__((ext_vector_type(8)));
typedef unsigned short u16x8 __attribute__((ext_vector_type(8)));

__device__ __forceinline__ float bf2f(unsigned short h) {
  return __uint_as_float(((unsigned int)h) << 16);
}
__device__ __forceinline__ unsigned short f2bf(float f) {
  unsigned int u = __float_as_uint(f);
  return (unsigned short)((u + 0x7FFFu + ((u >> 16) & 1u)) >> 16);
}
__device__ __forceinline__ void gld16(const unsigned short* g, unsigned short* l) {
  __builtin_amdgcn_global_load_lds(
      (__attribute__((address_space(1))) unsigned int*)(uintptr_t)g,
      (__attribute__((address_space(3))) unsigned int*)l, 16, 0, 0);
}

// position-space mask -> element-space mask for the anti-diagonal transpose layout:
// element 2c sits at position 15-c (low half), element 2c+1 at position 31-c (high half)
__device__ __forceinline__ unsigned pos2elem(unsigned m) {
  unsigned lo = __brev(m & 0xFFFFu) >> 16;   // bit i = m bit (15-i)
  unsigned hi = __brev(m >> 16) >> 16;       // bit i = m bit (31-i)
  lo = (lo | (lo << 8)) & 0x00FF00FFu;
  lo = (lo | (lo << 4)) & 0x0F0F0F0Fu;
  lo = (lo | (lo << 2)) & 0x33333333u;
  lo = (lo | (lo << 1)) & 0x55555555u;
  hi = (hi | (hi << 8)) & 0x00FF00FFu;
  hi = (hi | (hi << 4)) & 0x0F0F0F0Fu;
  hi = (hi | (hi << 2)) & 0x33333333u;
  hi = (hi | (hi << 1)) & 0x55555555u;
  return lo | (hi << 1);
}

// ---------------- column-wise l2 norms (axis=1) ----------------
__global__ __launch_bounds__(256) void knorm_part(const float* __restrict__ x, float* __restrict__ part,
                                                  int L, int SL, int NS) {
  int ls = blockIdx.x, hc = blockIdx.y, b = blockIdx.z, t = threadIdx.x;
  int h = hc * 256 + t;
  const float* xp = x + (size_t)b * L * 512 + h;
  float acc = 0.f;
  int l0 = ls * SL;
  for (int l = 0; l < SL; ++l) {
    float v = xp[(size_t)(l0 + l) * 512];
    acc += v * v;
  }
  part[(((size_t)b * 2 + hc) * NS + ls) * 256 + t] = acc;
}

__global__ __launch_bounds__(256) void knorm_fin(const float* __restrict__ part, float* __restrict__ inv, int NS) {
  int bh = blockIdx.x, t = threadIdx.x;
  float s = 0.f;
  for (int j = 0; j < NS; ++j) s += part[((size_t)bh * NS + j) * 256 + t];
  inv[(size_t)bh * 256 + t] = 1.f / fmaxf(sqrtf(s), 1e-12f);
}

__global__ __launch_bounds__(256) void kcast(const float* __restrict__ x, const float* __restrict__ inv,
                                             unsigned short* __restrict__ o, int shiftB, int total) {
  int i4 = (blockIdx.x * 256 + threadIdx.x) * 4;
  if (i4 >= total) return;
  int b = i4 >> shiftB;
  float4 v = *(const float4*)(x + i4);
  float4 nv = *(const float4*)(inv + (b << 9) + (i4 & 511));
  ushort4 r;
  r.x = f2bf(v.x * nv.x); r.y = f2bf(v.y * nv.y);
  r.z = f2bf(v.z * nv.z); r.w = f2bf(v.w * nv.w);
  *(ushort4*)(o + i4) = r;
}

// ---------------- weight prep: WcatT[1536][512] bf16 (B^T layout), bcat ----------------
__global__ __launch_bounds__(256) void kprepw(const float* __restrict__ Wq, const float* __restrict__ Wk,
                                              const float* __restrict__ Wv, unsigned short* __restrict__ WT) {
  __shared__ float T[32][33];
  int ti = blockIdx.x, tj = blockIdx.y, m = blockIdx.z;
  const float* W = m == 0 ? Wq : (m == 1 ? Wk : Wv);
  int c = threadIdx.x & 31, r0 = threadIdx.x >> 5;
#pragma unroll
  for (int j = 0; j < 4; ++j) {
    int r = r0 + j * 8;
    T[r][c] = W[(size_t)(ti * 32 + r) * 512 + tj * 32 + c];
  }
  __syncthreads();
#pragma unroll
  for (int j = 0; j < 4; ++j) {
    int r = r0 + j * 8;
    WT[(size_t)(m * 512 + tj * 32 + r) * 512 + ti * 32 + c] = f2bf(T[c][r]);
  }
}

__global__ void kprepb(const float* bq, const float* bk, const float* bv, float* bcat) {
  int i = blockIdx.x * 256 + threadIdx.x;
  if (i >= 1536) return;
  bcat[i] = i < 512 ? bq[i] : (i < 1024 ? bk[i - 512] : bv[i - 1024]);
}

// ---------------- bf16 MFMA GEMM: C[M,N] = A[M,K] @ Bt[N,K]^T + bias ----------------
__global__ __launch_bounds__(256) void kgemm(const unsigned short* __restrict__ A,
                                             const unsigned short* __restrict__ Bt,
                                             const float* __restrict__ bias,
                                             unsigned short* __restrict__ C,
                                             int K, int N) {
  __shared__ unsigned short As[128 * 32], Bs[128 * 32];
  int tid = threadIdx.x, lane = tid & 63, wave = tid >> 6;
  int m0 = blockIdx.y * 128, n0 = blockIdx.x * 128;
  f32x4 acc[4][4] = {};
  int wm = (wave >> 1) * 64, wn = (wave & 1) * 64;
  int frow = lane & 15, fk = (lane >> 4) * 8;
  for (int k0 = 0; k0 < K; k0 += 32) {
    if (k0) __syncthreads();
#pragma unroll
    for (int j = 0; j < 2; ++j) {
      int ch = j * 256 + tid;
      int row = ch >> 2, kc = (ch & 3) * 8;
      gld16(A + (size_t)(m0 + row) * K + k0 + kc, As + ch * 8);
      gld16(Bt + (size_t)(n0 + row) * K + k0 + kc, Bs + ch * 8);
    }
    __syncthreads();
    bf16x8 af[4], bfv[4];
#pragma unroll
    for (int mt = 0; mt < 4; ++mt) af[mt] = *(const bf16x8*)&As[(wm + mt * 16 + frow) * 32 + fk];
#pragma unroll
    for (int nt = 0; nt < 4; ++nt) bfv[nt] = *(const bf16x8*)&Bs[(wn + nt * 16 + frow) * 32 + fk];
#pragma unroll
    for (int mt = 0; mt < 4; ++mt)
#pragma unroll
      for (int nt = 0; nt < 4; ++nt)
        acc[mt][nt] = __builtin_amdgcn_mfma_f32_16x16x32_bf16(af[mt], bfv[nt], acc[mt][nt], 0, 0, 0);
  }
  int q = lane >> 4, c15 = lane & 15;
#pragma unroll
  for (int mt = 0; mt < 4; ++mt)
#pragma unroll
    for (int nt = 0; nt < 4; ++nt) {
      int col = n0 + wn + nt * 16 + c15;
      float bv = bias ? bias[col] : 0.f;
#pragma unroll
      for (int r = 0; r < 4; ++r) {
        int row = m0 + wm + mt * 16 + q * 4 + r;
        C[(size_t)row * N + col] = f2bf(acc[mt][nt][r] + bv);
      }
    }
}

// ---------------- fusion 1: Q=seqs(2048) K,V=smis(128); top-32 of 128 ----------------
// radix-select over ballots (exact, lax.top_k stable tie-break) + MFMA for P@V
__global__ __launch_bounds__(256) void kfusion1(const unsigned short* __restrict__ Pseqs,
                                                const unsigned short* __restrict__ Psmis,
                                                unsigned short* __restrict__ smil) {
  constexpr int PP = 136;                 // halfword pitch, rows 16B-aligned
  __shared__ unsigned short Sc[64 * PP];  // scores, then P (bf16)
  __shared__ unsigned short Vt[64 * PP];  // V^T [e][s]
  int tid = threadIdx.x, lane = tid & 63, w = tid >> 6;
  int lt = blockIdx.x, h = blockIdx.y, b = blockIdx.z;
  int l0 = lt * 64;
  int frow = lane & 15, q = lane >> 4, fk8 = q * 8;

  // stage V^T (coalesced global read, transposed LDS write; one-time cost)
  for (int ch = tid; ch < 1024; ch += 256) {
    int s = ch >> 3, e8 = (ch & 7) * 8;
    u16x8 vv = *(const u16x8*)&Psmis[(size_t)(b * 128 + s) * NC + 1024 + h * 64 + e8];
#pragma unroll
    for (int j = 0; j < 8; ++j) Vt[(e8 + j) * PP + s] = vv[j];
  }

  // scores: this wave's 16 Q-rows x 128 keys, fragments straight from global (L2-hot)
  {
    f32x4 acc[8] = {};
    const unsigned short* qrow = Pseqs + (size_t)(b * 2048 + l0 + w * 16 + frow) * NC + h * 64 + fk8;
#pragma unroll
    for (int ks = 0; ks < 2; ++ks) {
      bf16x8 a = *(const bf16x8*)(qrow + ks * 32);
#pragma unroll
      for (int nt = 0; nt < 8; ++nt) {
        bf16x8 bb = *(const bf16x8*)&Psmis[(size_t)(b * 128 + nt * 16 + frow) * NC + 512 + h * 64 + ks * 32 + fk8];
        acc[nt] = __builtin_amdgcn_mfma_f32_16x16x32_bf16(a, bb, acc[nt], 0, 0, 0);
      }
    }
#pragma unroll
    for (int nt = 0; nt < 8; ++nt)
#pragma unroll
      for (int r = 0; r < 4; ++r)
        Sc[(w * 16 + q * 4 + r) * PP + nt * 16 + frow] = f2bf(acc[nt][r]);
  }

  // per-row exact top-32 of 128 via 16-bit radix select on ballots, then softmax -> P
  uint64_t lmask = (1ull << lane) - 1ull;
  for (int i = 0; i < 16; ++i) {
    int off = (w * 16 + i) * PP;
    unsigned h0 = Sc[off + lane], h1 = Sc[off + 64 + lane];
    // monotone unsigned transform of bf16 bits
    unsigned t0 = (h0 & 0x8000u) ? (h0 ^ 0xFFFFu) : (h0 | 0x8000u);
    unsigned t1 = (h1 & 0x8000u) ? (h1 ^ 0xFFFFu) : (h1 | 0x8000u);
    unsigned act0 = 1u, act1 = 1u, Tv = 0u;
    int rem = 32;
#pragma unroll
    for (int bit = 15; bit >= 0; --bit) {
      unsigned b0 = act0 & (t0 >> bit);   // act in {0,1} => result is act && bit
      unsigned b1 = act1 & (t1 >> bit);
      int cnt = __popcll(__ballot((int)b0)) + __popcll(__ballot((int)b1));
      bool take = cnt >= rem;             // wave-uniform
      act0 = take ? b0 : (act0 ^ b0);
      act1 = take ? b1 : (act1 ^ b1);
      rem = take ? rem : rem - cnt;
      Tv = take ? (Tv | (1u << bit)) : Tv;
    }
    // ties (t == Tv): pick lowest original index first (stable like lax.top_k)
    uint64_t m0 = __ballot((int)act0), m1 = __ballot((int)act1);
    int pre0 = __popcll(m0 & lmask);
    int pre1 = __popcll(m0) + __popcll(m1 & lmask);
    int sel0 = (t0 > Tv) || (act0 && pre0 < rem);
    int sel1 = (t1 > Tv) || (act1 && pre1 < rem);
    unsigned hT = (Tv & 0x8000u) ? (Tv ^ 0x8000u) : (Tv ^ 0xFFFFu);
    float vT = bf2f((unsigned short)hT);  // min selected value: exponents in [0, tiny]
    float p0 = sel0 ? __expf((bf2f((unsigned short)h0) - vT) * 0.125f) : 0.f;
    float p1 = sel1 ? __expf((bf2f((unsigned short)h1) - vT) * 0.125f) : 0.f;
    float den = p0 + p1;
#pragma unroll
    for (int d = 1; d < 64; d <<= 1) den += __shfl_xor(den, d);
    float inv = 1.f / den;
    Sc[off + lane] = f2bf(p0 * inv);
    Sc[off + 64 + lane] = f2bf(p1 * inv);
  }
  __syncthreads();  // Vt (block-wide) + P ready

  // O = P[64x128] @ V[128x64] via MFMA (A = P rows, B = Vt rows)
  f32x4 oacc[4] = {};
#pragma unroll
  for (int k0 = 0; k0 < 128; k0 += 32) {
    bf16x8 a = *(const bf16x8*)&Sc[(w * 16 + frow) * PP + k0 + fk8];
#pragma unroll
    for (int nt = 0; nt < 4; ++nt) {
      bf16x8 bb = *(const bf16x8*)&Vt[(nt * 16 + frow) * PP + k0 + fk8];
      oacc[nt] = __builtin_amdgcn_mfma_f32_16x16x32_bf16(a, bb, oacc[nt], 0, 0, 0);
    }
  }
#pragma unroll
  for (int nt = 0; nt < 4; ++nt)
#pragma unroll
    for (int r = 0; r < 4; ++r)
      smil[(size_t)(b * 2048 + l0 + w * 16 + q * 4 + r) * 512 + h * 64 + nt * 16 + frow] = f2bf(oacc[nt][r]);
}

// ---------------- fusion 2 scores: S2[bh][l 128][s 2048] bf16 ----------------
__global__ __launch_bounds__(256) void kf2scores(const unsigned short* __restrict__ Psmis,
                                                 const unsigned short* __restrict__ Pseqs,
                                                 unsigned short* __restrict__ S2) {
  __shared__ unsigned short As[128 * 32], Bs[128 * 32];
  int tid = threadIdx.x, lane = tid & 63, wave = tid >> 6;
  int st = blockIdx.x, bh = blockIdx.y;
  int b = bh >> 3, h = bh & 7;
  int s0 = st * 128;
  const unsigned short* Abase = Psmis + (size_t)b * 128 * NC + h * 64;
  const unsigned short* Bbase = Pseqs + (size_t)b * 2048 * NC + 512 + h * 64;
  f32x4 acc[4][4] = {};
  int wm = (wave >> 1) * 64, wn = (wave & 1) * 64;
  int frow = lane & 15, fk = (lane >> 4) * 8;
  for (int k0 = 0; k0 < 64; k0 += 32) {
    if (k0) __syncthreads();
#pragma unroll
    for (int j = 0; j < 2; ++j) {
      int ch = j * 256 + tid;
      int row = ch >> 2, kc = (ch & 3) * 8;
      gld16(Abase + (size_t)row * NC + k0 + kc, As + ch * 8);
      gld16(Bbase + (size_t)(s0 + row) * NC + k0 + kc, Bs + ch * 8);
    }
    __syncthreads();
    bf16x8 af[4], bfv[4];
#pragma unroll
    for (int mt = 0; mt < 4; ++mt) af[mt] = *(const bf16x8*)&As[(wm + mt * 16 + frow) * 32 + fk];
#pragma unroll
    for (int nt = 0; nt < 4; ++nt) bfv[nt] = *(const bf16x8*)&Bs[(wn + nt * 16 + frow) * 32 + fk];
#pragma unroll
    for (int mt = 0; mt < 4; ++mt)
#pragma unroll
      for (int nt = 0; nt < 4; ++nt)
        acc[mt][nt] = __builtin_amdgcn_mfma_f32_16x16x32_bf16(af[mt], bfv[nt], acc[mt][nt], 0, 0, 0);
  }
  int q = lane >> 4, c15 = lane & 15;
  unsigned short* outp = S2 + (size_t)bh * 128 * 2048;
#pragma unroll
  for (int mt = 0; mt < 4; ++mt)
#pragma unroll
    for (int nt = 0; nt < 4; ++nt)
#pragma unroll
      for (int r = 0; r < 4; ++r)
        outp[(size_t)(wm + mt * 16 + q * 4 + r) * 2048 + s0 + wn + nt * 16 + c15] = f2bf(acc[mt][nt][r]);
}

// ---------------- fusion 2 select: top-32 of 2048 per row via bit-plane radix select ----------------
// per wave: one row. 64 lanes x 32 keys. Anti-diagonal bit transpose -> plane pl in B[15-pl],
// 16-step radix select with butterfly counts, masks remapped to element space for exact
// lowest-index-first tie order, compact to LDS, coalesced AV.
__global__ __launch_bounds__(256) void kf2select(const unsigned short* __restrict__ S2,
                                                 const unsigned short* __restrict__ Pseqs,
                                                 float* __restrict__ seqs_out) {
  __shared__ float pS[4][32];
  __shared__ int   sS[4][32];
  int tid = threadIdx.x, lane = tid & 63, w = tid >> 6;
  int rid = blockIdx.x * 4 + w;
  int l = rid & 127, bh = rid >> 7;
  int h = bh & 7, b = bh >> 3;
  const unsigned short* rowp = S2 + (size_t)rid * 2048;

  // load this lane's 32 bf16 keys as 16 packed dwords
  unsigned B[16];
  const uint4* p4 = (const uint4*)(rowp + lane * 32);
#pragma unroll
  for (int i = 0; i < 4; ++i) {
    uint4 qv = p4[i];
    B[i * 4 + 0] = qv.x; B[i * 4 + 1] = qv.y; B[i * 4 + 2] = qv.z; B[i * 4 + 3] = qv.w;
  }
  // packed monotone transform: per half, t = sign ? h^0xFFFF : h|0x8000
#pragma unroll
  for (int i = 0; i < 16; ++i) {
    unsigned s = (B[i] >> 15) & 0x00010001u;
    B[i] = B[i] ^ (s * 0x7FFFu) ^ 0x80008000u;
  }
  // 16-dword bit-matrix block-swap network. This is the ANTI-diagonal transpose:
  // final B[idx] holds bit-plane (15-idx); mask position p maps to element
  // e = 2*(15-p) for p<16, e = 2*(31-p)+1 for p>=16 (handled by pos2elem()).
  {
    unsigned t;
#define TSTEP(k, j, mm) t = (B[k] ^ (B[(k)+(j)] >> (j))) & (mm); B[k] ^= t; B[(k)+(j)] ^= (t << (j));
    TSTEP(0,8,0x00FF00FFu) TSTEP(1,8,0x00FF00FFu) TSTEP(2,8,0x00FF00FFu) TSTEP(3,8,0x00FF00FFu)
    TSTEP(4,8,0x00FF00FFu) TSTEP(5,8,0x00FF00FFu) TSTEP(6,8,0x00FF00FFu) TSTEP(7,8,0x00FF00FFu)
    TSTEP(0,4,0x0F0F0F0Fu) TSTEP(1,4,0x0F0F0F0Fu) TSTEP(2,4,0x0F0F0F0Fu) TSTEP(3,4,0x0F0F0F0Fu)
    TSTEP(8,4,0x0F0F0F0Fu) TSTEP(9,4,0x0F0F0F0Fu) TSTEP(10,4,0x0F0F0F0Fu) TSTEP(11,4,0x0F0F0F0Fu)
    TSTEP(0,2,0x33333333u) TSTEP(1,2,0x33333333u) TSTEP(4,2,0x33333333u) TSTEP(5,2,0x33333333u)
    TSTEP(8,2,0x33333333u) TSTEP(9,2,0x33333333u) TSTEP(12,2,0x33333333u) TSTEP(13,2,0x33333333u)
    TSTEP(0,1,0x55555555u) TSTEP(2,1,0x55555555u) TSTEP(4,1,0x55555555u) TSTEP(6,1,0x55555555u)
    TSTEP(8,1,0x55555555u) TSTEP(10,1,0x55555555u) TSTEP(12,1,0x55555555u) TSTEP(14,1,0x55555555u)
#undef TSTEP
  }
  // radix select MSB->LSB (plane `bit` lives in B[15-bit])
  unsigned act = 0xFFFFFFFFu, gt = 0u, Tv = 0u;
  int rem = 32;
#pragma unroll
  for (int bit = 15; bit >= 0; --bit) {
    unsigned bm = B[15 - bit] & act;
    int c = __popc(bm);
#pragma unroll
    for (int d = 1; d < 64; d <<= 1) c += __shfl_xor(c, d);
    bool take = (c >= rem);
    unsigned actx = act ^ bm;
    act = take ? bm : actx;
    gt = take ? gt : (gt | bm);
    rem = take ? rem : (rem - c);
    Tv = take ? (Tv | (1u << bit)) : Tv;
  }
  unsigned hT = (Tv & 0x8000u) ? (Tv ^ 0x8000u) : (Tv ^ 0xFFFFu);
  float vT = bf2f((unsigned short)hT);

  // remap masks to element space so ctz iterates ascending element index
  gt = pos2elem(gt);
  act = pos2elem(act);

  // tie-fill: need `rem` elements from act (== Tv), lane-major then ascending index
  int pc_tie = __popc(act);
  int inc = pc_tie;
#pragma unroll
  for (int d = 1; d < 64; d <<= 1) { int y = __shfl_up(inc, d); if (lane >= d) inc += y; }
  int tie_pre = inc - pc_tie;
  int budget = rem - tie_pre;
  budget = budget < 0 ? 0 : (budget > pc_tie ? pc_tie : budget);
  int total_lane = __popc(gt) + budget;
  int inc2 = total_lane;
#pragma unroll
  for (int d = 1; d < 64; d <<= 1) { int y = __shfl_up(inc2, d); if (lane >= d) inc2 += y; }
  int slot = inc2 - total_lane;

  // extract selected: exp + compact (p, idx) to LDS
  float lsum = 0.f;
  unsigned m = gt;
  while (m) {
    int e = __builtin_ctz(m); m &= m - 1;
    int gidx = (lane << 5) + e;
    float v = bf2f(rowp[gidx]);
    float ev = __expf((v - vT) * 0.125f);
    pS[w][slot] = ev; sS[w][slot] = gidx; ++slot; lsum += ev;
  }
  m = act;
  for (int taken = 0; taken < budget; ++taken) {
    int e = __builtin_ctz(m); m &= m - 1;
    int gidx = (lane << 5) + e;
    float v = bf2f(rowp[gidx]);
    float ev = __expf((v - vT) * 0.125f);
    pS[w][slot] = ev; sS[w][slot] = gidx; ++slot; lsum += ev;
  }
  float den = lsum;
#pragma unroll
  for (int d = 1; d < 64; d <<= 1) den += __shfl_xor(den, d);

  // AV: coalesced gather of 32 selected V rows
  float acc = 0.f;
  const unsigned short* Vb = Pseqs + (size_t)(b * 2048) * NC + 1024 + h * 64 + lane;
#pragma unroll 8
  for (int t = 0; t < 32; ++t) {
    float pv = pS[w][t];
    int s = sS[w][t];
    acc += pv * bf2f(Vb[(size_t)s * NC]);
  }
  seqs_out[(size_t)(b * 128 + l) * 512 + h * 64 + lane] = acc / den;
}

// ---------------- pooling ----------------
__device__ __forceinline__ float dot8(uint4 pk, const float* w) {
  float s = bf2f((unsigned short)(pk.x & 0xFFFFu)) * w[0] + bf2f((unsigned short)(pk.x >> 16)) * w[1];
  s += bf2f((unsigned short)(pk.y & 0xFFFFu)) * w[2] + bf2f((unsigned short)(pk.y >> 16)) * w[3];
  s += bf2f((unsigned short)(pk.z & 0xFFFFu)) * w[4] + bf2f((unsigned short)(pk.z >> 16)) * w[5];
  s += bf2f((unsigned short)(pk.w & 0xFFFFu)) * w[6] + bf2f((unsigned short)(pk.w >> 16)) * w[7];
  return s;
}

__global__ __launch_bounds__(256) void kpool1a(const unsigned short* __restrict__ x,
                                               const float* __restrict__ wp, const float* __restrict__ bp,
                                               float* __restrict__ logits) {
  int tid = threadIdx.x, lane = tid & 63, wave = tid >> 6;
  int r = blockIdx.x * 4 + wave;
  uint4 pk = *(const uint4*)(x + (size_t)r * 512 + lane * 8);
  float acc = dot8(pk, wp + lane * 8);
#pragma unroll
  for (int d = 1; d < 64; d <<= 1) acc += __shfl_xor(acc, d);
  if (lane == 0) logits[r] = acc + bp[0];
}

__global__ __launch_bounds__(256) void kpool1b(const unsigned short* __restrict__ x,
                                               const float* __restrict__ logits,
                                               float* __restrict__ aout, float* __restrict__ pp) {
  __shared__ float red[256];
  __shared__ float aS[256];
  int t = threadIdx.x;
  int b = blockIdx.x >> 3, ls = blockIdx.x & 7;
  const float* lg = logits + b * 2048;
  float lm = -FLT_MAX;
  for (int j = t; j < 2048; j += 256) lm = fmaxf(lm, lg[j]);
  red[t] = lm; __syncthreads();
  for (int s = 128; s > 0; s >>= 1) { if (t < s) red[t] = fmaxf(red[t], red[t + s]); __syncthreads(); }
  float M = red[0]; __syncthreads();
  float sm = 0.f;
  for (int j = t; j < 2048; j += 256) sm += __expf(lg[j] - M);
  red[t] = sm; __syncthreads();
  for (int s = 128; s > 0; s >>= 1) { if (t < s) red[t] += red[t + s]; __syncthreads(); }
  float D = red[0];
  int l0 = ls * 256;
  float a = __expf(lg[l0 + t] - M) / D;
  aS[t] = a;
  aout[b * 2048 + l0 + t] = a;
  __syncthreads();
  float acc0 = 0.f, acc1 = 0.f;
  const unsigned short* xb = x + ((size_t)b * 2048 + l0) * 512;
#pragma unroll 4
  for (int ll = 0; ll < 256; ++ll) {
    float av = aS[ll];
    acc0 += av * bf2f(xb[(size_t)ll * 512 + t]);
    acc1 += av * bf2f(xb[(size_t)ll * 512 + t + 256]);
  }
  pp[(size_t)(b * 8 + ls) * 512 + t] = acc0;
  pp[(size_t)(b * 8 + ls) * 512 + t + 256] = acc1;
}

__global__ __launch_bounds__(256) void kpool2(const float* __restrict__ x,
                                              const float* __restrict__ wp, const float* __restrict__ bp,
                                              float* __restrict__ a2out, float* __restrict__ pooled2) {
  __shared__ float lgS[128];
  int t = threadIdx.x, lane = t & 63, wave = t >> 6;
  int b = blockIdx.x;
  for (int i = 0; i < 32; ++i) {
    int row = wave * 32 + i;
    const float* xp = x + (size_t)(b * 128 + row) * 512;
    float acc = 0.f;
#pragma unroll
    for (int j = 0; j < 8; ++j) acc += xp[lane + 64 * j] * wp[lane + 64 * j];
#pragma unroll
    for (int d = 1; d < 64; d <<= 1) acc += __shfl_xor(acc, d);
    if (lane == 0) lgS[row] = acc + bp[0];
  }
  __syncthreads();
  if (wave == 0) {
    float a0 = lgS[lane], a1 = lgS[64 + lane];
    float m = fmaxf(a0, a1);
#pragma unroll
    for (int d = 1; d < 64; d <<= 1) m = fmaxf(m, __shfl_xor(m, d));
    float e0 = __expf(a0 - m), e1 = __expf(a1 - m);
    float sden = e0 + e1;
#pragma unroll
    for (int d = 1; d < 64; d <<= 1) sden += __shfl_xor(sden, d);
    a0 = e0 / sden; a1 = e1 / sden;
    lgS[lane] = a0; lgS[64 + lane] = a1;
    a2out[b * 128 + lane] = a0;
    a2out[b * 128 + 64 + lane] = a1;
  }
  __syncthreads();
  float acc0 = 0.f, acc1 = 0.f;
#pragma unroll 4
  for (int row = 0; row < 128; ++row) {
    float av = lgS[row];
    const float* xp = x + (size_t)(b * 128 + row) * 512;
    acc0 += av * xp[t];
    acc1 += av * xp[t + 256];
  }
  pooled2[(size_t)b * 512 + t] = acc0;
  pooled2[(size_t)b * 512 + t + 256] = acc1;
}

// ---------------- head ----------------
__global__ __launch_bounds__(256) void kemb(const float* __restrict__ pp, const float* __restrict__ pooled2,
                                            float* __restrict__ embo, float* __restrict__ embws) {
  __shared__ float red[256];
  int t = threadIdx.x, b = blockIdx.x;
  float pre[4];
#pragma unroll
  for (int qq = 0; qq < 4; ++qq) {
    int c = qq * 256 + t;
    float s;
    if (c < 512) {
      s = 0.f;
      for (int lsl = 0; lsl < 8; ++lsl) s += pp[(size_t)(b * 8 + lsl) * 512 + c];
    } else {
      s = pooled2[(size_t)b * 512 + (c - 512)];
    }
    pre[qq] = s;
  }
  float ssq = pre[0] * pre[0] + pre[1] * pre[1] + pre[2] * pre[2] + pre[3] * pre[3];
  red[t] = ssq; __syncthreads();
  for (int s2 = 128; s2 > 0; s2 >>= 1) { if (t < s2) red[t] += red[t + s2]; __syncthreads(); }
  float inv = 1.f / fmaxf(sqrtf(red[0]), 1e-12f);
#pragma unroll
  for (int qq = 0; qq < 4; ++qq) {
    int c = qq * 256 + t;
    float e = pre[qq] * inv;
    embo[(size_t)b * 1024 + c] = e;
    embws[(size_t)b * 1024 + c] = e;
  }
}

__global__ __launch_bounds__(256) void kmlp(const float* __restrict__ in, const float* __restrict__ W,
                                            const float* __restrict__ bias, float* __restrict__ out,
                                            int IN, int ON) {
  __shared__ float e[1024];
  int t = threadIdx.x;
  int chunks = ON >> 8;
  int b = blockIdx.x / chunks, jc = blockIdx.x % chunks;
  for (int q = t; q < IN; q += 256) e[q] = in[(size_t)b * IN + q];
  __syncthreads();
  int j = jc * 256 + t;
  float acc = bias[j];
#pragma unroll 8
  for (int i = 0; i < IN; ++i) acc += e[i] * W[(size_t)i * ON + j];
  out[(size_t)b * ON + j] = fmaxf(acc, 0.f);
}

__global__ void kout(const float* __restrict__ h2, const float* __restrict__ W3, const float* __restrict__ b3,
                     float* __restrict__ outp) {
  int b = blockIdx.x, lane = threadIdx.x;
  float acc = 0.f;
#pragma unroll
  for (int j = 0; j < 8; ++j) acc += h2[(size_t)b * 512 + lane + 64 * j] * W3[lane + 64 * j];
#pragma unroll
  for (int d = 1; d < 64; d <<= 1) acc += __shfl_xor(acc, d);
  if (lane == 0) outp[b] = acc + b3[0];
}

// ---------------- launch ----------------
extern "C" void kernel_launch(void* const* d_in, const int* in_sizes, int n_in,
                              void* d_out, int out_size, void* d_ws, size_t ws_size,
                              hipStream_t stream) {
  const float* seqs = (const float*)d_in[0];
  const float* smis = (const float*)d_in[1];
  const float* Wq = (const float*)d_in[2];
  const float* bq = (const float*)d_in[3];
  const float* Wk = (const float*)d_in[4];
  const float* bk = (const float*)d_in[5];
  const float* Wv = (const float*)d_in[6];
  const float* bv = (const float*)d_in[7];
  const float* wp = (const float*)d_in[8];
  const float* bp = (const float*)d_in[9];
  const float* W1 = (const float*)d_in[10];
  const float* b1 = (const float*)d_in[11];
  const float* W2 = (const float*)d_in[12];
  const float* b2 = (const float*)d_in[13];
  const float* W3 = (const float*)d_in[14];
  const float* b3 = (const float*)d_in[15];
  float* out = (float*)d_out;
  char* ws = (char*)d_ws;

  float* nrm_s = (float*)(ws + WS_NRM_S);
  float* nrm_m = (float*)(ws + WS_NRM_M);
  float* part_s = (float*)(ws + WS_PART);
  float* part_m = (float*)(ws + WS_PARTM);
  float* bcat = (float*)(ws + WS_BCAT);
  float* log1 = (float*)(ws + WS_LOG1);
  float* pp1 = (float*)(ws + WS_PP1);
  float* pooled2 = (float*)(ws + WS_POOL2);
  float* embws = (float*)(ws + WS_EMB);
  float* h1 = (float*)(ws + WS_H1);
  float* h2 = (float*)(ws + WS_H2);
  unsigned short* wct = (unsigned short*)(ws + WS_WCT);
  unsigned short* smis_nb = (unsigned short*)(ws + WS_SMISNB);
  unsigned short* Psmis = (unsigned short*)(ws + WS_PSMIS);
  float* seqs_out = (float*)(ws + WS_SEQSOUT);
  unsigned short* seqs_nb = (unsigned short*)(ws + WS_SEQSNB);
  unsigned short* Pseqs = (unsigned short*)(ws + WS_PSEQS);
  unsigned short* smil = (unsigned short*)(ws + WS_SMILOUT);
  unsigned short* S2 = (unsigned short*)(ws + WS_S2);

  // 1. column norms
  knorm_part<<<dim3(8, 2, 16), 256, 0, stream>>>(seqs, part_s, 2048, 256, 8);
  knorm_part<<<dim3(1, 2, 16), 256, 0, stream>>>(smis, part_m, 128, 128, 1);
  knorm_fin<<<dim3(32), 256, 0, stream>>>(part_s, nrm_s, 8);
  knorm_fin<<<dim3(32), 256, 0, stream>>>(part_m, nrm_m, 1);
  // 2. normalize + cast to bf16
  kcast<<<dim3(16384), 256, 0, stream>>>(seqs, nrm_s, seqs_nb, 20, 16 * 2048 * 512);
  kcast<<<dim3(1024), 256, 0, stream>>>(smis, nrm_m, smis_nb, 16, 16 * 128 * 512);
  // 3. weight prep
  kprepw<<<dim3(16, 16, 3), 256, 0, stream>>>(Wq, Wk, Wv, wct);
  kprepb<<<dim3(6), 256, 0, stream>>>(bq, bk, bv, bcat);
  // 4. fused QKV projections
  kgemm<<<dim3(12, 256), 256, 0, stream>>>(seqs_nb, wct, bcat, Pseqs, 512, NC);
  kgemm<<<dim3(12, 16), 256, 0, stream>>>(smis_nb, wct, bcat, Psmis, 512, NC);
  // 5. fusion 1 attention (writes smil, aliases dead seqs_nb)
  kfusion1<<<dim3(32, 8, 16), 256, 0, stream>>>(Pseqs, Psmis, smil);
  // 6. pool 1
  kpool1a<<<dim3(8192), 256, 0, stream>>>(smil, wp, bp, log1);
  kpool1b<<<dim3(128), 256, 0, stream>>>(smil, log1, out + OUT_A1, pp1);
  // 7. fusion 2
  kf2scores<<<dim3(16, 128), 256, 0, stream>>>(Psmis, Pseqs, S2);
  kf2select<<<dim3(4096), 256, 0, stream>>>(S2, Pseqs, seqs_out);
  kpool2<<<dim3(16), 256, 0, stream>>>(seqs_out, wp, bp, out + OUT_A2, pooled2);
  // 8. head
  kemb<<<dim3(16), 256, 0, stream>>>(pp1, pooled2, out + OUT_EMB, embws);
  kmlp<<<dim3(64), 256, 0, stream>>>(embws, W1, b1, h1, 1024, 1024);
  kmlp<<<dim3(32), 256, 0, stream>>>(h1, W2, b2, h2, 1024, 512);
  kout<<<dim3(16), 64, 0, stream>>>(h2, W3, b3, out + OUT_OUT);
}